// Round 1
// baseline (244.517 us; speedup 1.0000x reference)
//
#include <hip/hip_runtime.h>
#include <hip/hip_bf16.h>
#include <stdint.h>

// out = X @ W^T + 0.01*(|X| @ |W|^T) - 1e-6, all 4096x4096, fp32 in/out.
// Strategy: convert X,W to bf16 in d_ws, then dual-accumulator MFMA GEMM
// (signed + abs share staging; abs fragments made by ANDing sign bits off).

#define NDIM 4096
#define KDIM 4096

typedef __attribute__((ext_vector_type(8))) __bf16 bf16x8;
typedef __attribute__((ext_vector_type(8))) unsigned short u16x8;
typedef __attribute__((ext_vector_type(4))) float f32x4;
typedef __attribute__((ext_vector_type(4))) int i32x4;

// ---------------- fp32 -> bf16 (RNE), 8 elems/thread ----------------
__global__ __launch_bounds__(256) void f32_to_bf16_kernel(
    const float* __restrict__ src, unsigned short* __restrict__ dst, int n8) {
  int i = blockIdx.x * 256 + threadIdx.x;
  if (i >= n8) return;
  const float4* sp = reinterpret_cast<const float4*>(src) + (size_t)i * 2;
  float4 a = sp[0];
  float4 b = sp[1];
  float v[8] = {a.x, a.y, a.z, a.w, b.x, b.y, b.z, b.w};
  u16x8 r;
#pragma unroll
  for (int j = 0; j < 8; ++j) {
    uint32_t u = __builtin_bit_cast(uint32_t, v[j]);
    u += 0x7FFFu + ((u >> 16) & 1u);  // round-to-nearest-even
    r[j] = (unsigned short)(u >> 16);
  }
  *reinterpret_cast<u16x8*>(dst + (size_t)i * 8) = r;
}

// ---------------- dual GEMM: C = X@W^T (+0.01*abs path) ----------------
// Tile 128x128, BK=64. 512 threads = 8 waves in 2x4 grid; wave tile 64x32.
// LDS rows are 128B: XOR-swizzle 16B granule with (row&7), applied via
// pre-swizzled GLOBAL source (global_load_lds dest must stay linear).
__global__ __launch_bounds__(512, 2) void gemm_dual_kernel(
    const unsigned short* __restrict__ Xb, const unsigned short* __restrict__ Wb,
    float* __restrict__ out) {
  __shared__ alignas(16) unsigned short As[128 * 64];
  __shared__ alignas(16) unsigned short Bs[128 * 64];

  const int tid = threadIdx.x;
  const int l = tid & 63;
  const int w = tid >> 6;  // wave 0..7
  const int wr = w >> 2;   // 0..1  (M)
  const int wc = w & 3;    // 0..3  (N)

  const int bm = blockIdx.x & 31;
  const int bn = blockIdx.x >> 5;
  const int row0 = bm << 7;
  const int col0 = bn << 7;

  // --- staging: wave w covers 8 rows per 1KB chunk; r&7 == l>>3 here ---
  const int rsub = (w << 3) + (l >> 3);   // 0..63 (chunk-relative row)
  const int gsrc = (l & 7) ^ (l >> 3);    // swizzled source granule
  const unsigned short* aSrc = Xb + (size_t)(row0 + rsub) * KDIM + gsrc * 8;
  const unsigned short* bSrc = Wb + (size_t)(col0 + rsub) * KDIM + gsrc * 8;
  unsigned short* aDst0 = As + w * 512;   // wave-uniform LDS base (bytes: w*1024)
  unsigned short* bDst0 = Bs + w * 512;

  // --- fragment read offsets (elements) ---
  // A-frag (16x32): lane l holds row (l&15), k = (l>>4)*8 + 0..7
  const int lr = l & 15;
  const int kq = l >> 4;              // 0..3
  const int g0 = kq ^ (lr & 7);       // swizzled granule for kk=0
  int aRow[4], bRow[2];
#pragma unroll
  for (int fm = 0; fm < 4; ++fm) aRow[fm] = ((wr << 6) + (fm << 4) + lr) * 64;
#pragma unroll
  for (int fn = 0; fn < 2; ++fn) bRow[fn] = ((wc << 5) + (fn << 4) + lr) * 64;
  const int gE0 = g0 * 8;
  const int gE1 = (g0 ^ 4) * 8;  // kk=1: granule = (kq+4) ^ (lr&7) = g0 ^ 4

  f32x4 accS[4][2], accA[4][2];
#pragma unroll
  for (int i = 0; i < 4; ++i)
#pragma unroll
    for (int j = 0; j < 2; ++j) {
      accS[i][j] = (f32x4)0.0f;
      accA[i][j] = (f32x4)0.0f;
    }

  const int NT = KDIM / 64;
  for (int kt = 0; kt < NT; ++kt) {
    {
      const unsigned short* ap = aSrc + kt * 64;
      const unsigned short* bp = bSrc + kt * 64;
      __builtin_amdgcn_global_load_lds(
          (const __attribute__((address_space(1))) void*)ap,
          (__attribute__((address_space(3))) void*)aDst0, 16, 0, 0);
      __builtin_amdgcn_global_load_lds(
          (const __attribute__((address_space(1))) void*)(ap + (size_t)64 * KDIM),
          (__attribute__((address_space(3))) void*)(aDst0 + 4096), 16, 0, 0);
      __builtin_amdgcn_global_load_lds(
          (const __attribute__((address_space(1))) void*)bp,
          (__attribute__((address_space(3))) void*)bDst0, 16, 0, 0);
      __builtin_amdgcn_global_load_lds(
          (const __attribute__((address_space(1))) void*)(bp + (size_t)64 * KDIM),
          (__attribute__((address_space(3))) void*)(bDst0 + 4096), 16, 0, 0);
    }
    __syncthreads();

#pragma unroll
    for (int kk = 0; kk < 2; ++kk) {
      const int gE = (kk == 0) ? gE0 : gE1;
      i32x4 aR[4], bR[2], aAbs[4], bAbs[2];
#pragma unroll
      for (int fm = 0; fm < 4; ++fm) {
        aR[fm] = *reinterpret_cast<const i32x4*>(As + aRow[fm] + gE);
        aAbs[fm] = aR[fm] & 0x7FFF7FFF;
      }
#pragma unroll
      for (int fn = 0; fn < 2; ++fn) {
        bR[fn] = *reinterpret_cast<const i32x4*>(Bs + bRow[fn] + gE);
        bAbs[fn] = bR[fn] & 0x7FFF7FFF;
      }
#pragma unroll
      for (int fm = 0; fm < 4; ++fm)
#pragma unroll
        for (int fn = 0; fn < 2; ++fn) {
          accS[fm][fn] = __builtin_amdgcn_mfma_f32_16x16x32_bf16(
              __builtin_bit_cast(bf16x8, aR[fm]), __builtin_bit_cast(bf16x8, bR[fn]),
              accS[fm][fn], 0, 0, 0);
          accA[fm][fn] = __builtin_amdgcn_mfma_f32_16x16x32_bf16(
              __builtin_bit_cast(bf16x8, aAbs[fm]), __builtin_bit_cast(bf16x8, bAbs[fn]),
              accA[fm][fn], 0, 0, 0);
        }
    }
    __syncthreads();
  }

  // --- epilogue: C/D layout col=lane&15, row=(lane>>4)*4+j (m89-verified) ---
  const int orow = row0 + (wr << 6) + kq * 4;
  const int ocol = col0 + (wc << 5) + lr;
#pragma unroll
  for (int fm = 0; fm < 4; ++fm)
#pragma unroll
    for (int fn = 0; fn < 2; ++fn)
#pragma unroll
      for (int j = 0; j < 4; ++j) {
        int r = orow + fm * 16 + j;
        int c = ocol + fn * 16;
        out[(size_t)r * NDIM + c] = accS[fm][fn][j] + 0.01f * accA[fm][fn][j] - 1e-6f;
      }
}

extern "C" void kernel_launch(void* const* d_in, const int* in_sizes, int n_in,
                              void* d_out, int out_size, void* d_ws, size_t ws_size,
                              hipStream_t stream) {
  const float* X = (const float*)d_in[0];
  const float* W = (const float*)d_in[1];
  float* out = (float*)d_out;
  unsigned short* Xb = (unsigned short*)d_ws;
  unsigned short* Wb = Xb + (size_t)NDIM * KDIM;

  const int n8 = (NDIM * KDIM) / 8;  // 2,097,152
  const int cblocks = n8 / 256;      // 8,192
  hipLaunchKernelGGL(f32_to_bf16_kernel, dim3(cblocks), dim3(256), 0, stream, X, Xb, n8);
  hipLaunchKernelGGL(f32_to_bf16_kernel, dim3(cblocks), dim3(256), 0, stream, W, Wb, n8);
  hipLaunchKernelGGL(gemm_dual_kernel, dim3((NDIM / 128) * (NDIM / 128)), dim3(512), 0,
                     stream, Xb, Wb, out);
}